// Round 3
// baseline (251.683 us; speedup 1.0000x reference)
//
#include <hip/hip_runtime.h>

// TransformerDecoderLayer: B=4,S=2048,D=512,H=8,DK=64,DFF=2048, fp32 in/out.
// bf16 MFMA GEMMs (global_load_lds staging + XOR chunk swizzle) +
// swapped-QK^T flash attention (32q/wave, XOR-swizzled LDS, cvt_pk softmax,
// mask bitmap + reg prefetch + defer-max) + fp32 LN.

typedef __bf16 bf16x8 __attribute__((ext_vector_type(8)));
typedef float f32x4 __attribute__((ext_vector_type(4)));
typedef unsigned short us4 __attribute__((ext_vector_type(4)));

__device__ __forceinline__ unsigned short f2bf(float f){
  unsigned u = __builtin_bit_cast(unsigned, f);
  u += 0x7fffu + ((u >> 16) & 1u);   // RNE
  return (unsigned short)(u >> 16);
}

__device__ __forceinline__ unsigned cvt_pk_bf16(float lo, float hi){
  unsigned r;
  asm("v_cvt_pk_bf16_f32 %0, %1, %2" : "=v"(r) : "v"(lo), "v"(hi));
  return r;
}

typedef const __attribute__((address_space(1))) void* gas_t;
typedef __attribute__((address_space(3))) void* las_t;
__device__ __forceinline__ void gl_lds16(const void* g, void* l){
  __builtin_amdgcn_global_load_lds((gas_t)g, (las_t)l, 16, 0, 0);
}

// ---------- f32 -> bf16 convert (4 elems/thread) ----------
__global__ void k_f2b(const float* __restrict__ in, unsigned short* __restrict__ out, int n4){
  int i = blockIdx.x * 256 + threadIdx.x;
  if (i < n4){
    float4 v = reinterpret_cast<const float4*>(in)[i];
    us4 o = { f2bf(v.x), f2bf(v.y), f2bf(v.z), f2bf(v.w) };
    reinterpret_cast<us4*>(out)[i] = o;
  }
}

// ---------- weight transpose+convert: in[K][N] f32 -> out[N][K] bf16 ----------
__global__ void k_wtrans(const float* __restrict__ in, unsigned short* __restrict__ out, int K, int N){
  __shared__ float t[32][33];
  int k0 = blockIdx.x*32, n0 = blockIdx.y*32;
  int tx = threadIdx.x & 31, ty = threadIdx.x >> 5;
  #pragma unroll
  for (int r = 0; r < 4; ++r)
    t[ty + 8*r][tx] = in[(size_t)(k0 + ty + 8*r)*N + n0 + tx];
  __syncthreads();
  #pragma unroll
  for (int r = 0; r < 4; ++r)
    out[(size_t)(n0 + ty + 8*r)*K + k0 + tx] = f2bf(t[tx][ty + 8*r]);
}

// qkv weights [H,512,64] (x3) -> Wt_qkv[1536][512], row n = sel*512 + h*64 + e
__global__ void k_wtrans_qkv(const float* __restrict__ qw, const float* __restrict__ kw,
                             const float* __restrict__ vw, unsigned short* __restrict__ out){
  __shared__ float t[32][33];
  int z = blockIdx.z, sel = z >> 3, h = z & 7;
  const float* in = (sel==0 ? qw : (sel==1 ? kw : vw)) + (size_t)h*512*64;
  unsigned short* o = out + ((size_t)(sel*512 + h*64)) * 512;
  int k0 = blockIdx.x*32, n0 = blockIdx.y*32;
  int tx = threadIdx.x & 31, ty = threadIdx.x >> 5;
  #pragma unroll
  for (int r = 0; r < 4; ++r)
    t[ty + 8*r][tx] = in[(size_t)(k0 + ty + 8*r)*64 + n0 + tx];
  __syncthreads();
  #pragma unroll
  for (int r = 0; r < 4; ++r)
    o[(size_t)(n0 + ty + 8*r)*512 + k0 + tx] = f2bf(t[tx][ty + 8*r]);
}

__global__ void k_bqkv(const float* __restrict__ qb, const float* __restrict__ kb,
                       const float* __restrict__ vb, float* __restrict__ out){
  int n = blockIdx.x*256 + threadIdx.x;
  if (n < 1536){ int sel = n >> 9, r = n & 511;
    out[n] = (sel==0 ? qb : (sel==1 ? kb : vb))[r]; }
}

// ---------- mask tile bitmap: out16[b*32+qt64][half] bit i = tile(qt64, half*16+i) all-ones ----------
__global__ __launch_bounds__(256) void k_maskbits(const int* __restrict__ mask, unsigned short* __restrict__ out){
  const int tid = threadIdx.x;
  const int bq = blockIdx.x;            // b*32 + qt64
  const int half = blockIdx.y;          // kt halves
  const int b = bq >> 5, qt = bq & 31;
  const int* base = mask + (size_t)b*2048*2048 + (size_t)(qt*64 + (tid>>4)*4)*2048 + (tid&15)*4;
  unsigned bits = 0;
  for (int i = 0; i < 16; ++i){
    const int* p = base + (half*16 + i)*64;
    int ok = 1;
    #pragma unroll
    for (int r = 0; r < 4; ++r){
      int4 v = *reinterpret_cast<const int4*>(p + (size_t)r*2048);
      ok &= (v.x!=0)&(v.y!=0)&(v.z!=0)&(v.w!=0);
    }
    bits |= (unsigned)ok << i;
  }
  #pragma unroll
  for (int o = 1; o < 64; o <<= 1) bits &= __shfl_xor(bits, o);
  __shared__ unsigned red[4];
  if ((tid & 63) == 0) red[tid >> 6] = bits;
  __syncthreads();
  if (tid == 0) out[bq*2 + half] = (unsigned short)(red[0]&red[1]&red[2]&red[3]);
}

// ---------- GEMM: C[M,N] = A[M,K](bf16) * Bt[N,K]^T (bf16) + bias, fused epilogues ----------
template<int MODE>
__global__ __launch_bounds__(256, 3) void k_gemm(
    const unsigned short* __restrict__ A, const unsigned short* __restrict__ Bt,
    const float* __restrict__ bias, const float* __restrict__ resid,
    unsigned short* __restrict__ ob0, unsigned short* __restrict__ ob1, unsigned short* __restrict__ ob2,
    float* __restrict__ of, int M, int N, int K)
{
  __shared__ unsigned short As[128*32];   // linear [128][32]
  __shared__ unsigned short Bs[128*32];
  const int tid = threadIdx.x, lane = tid & 63, wid = tid >> 6;
  const int g = lane >> 4, lr = lane & 15;
  const int rowBase = blockIdx.x * 128, colBase = blockIdx.y * 128;
  const int wr = (wid >> 1) * 64, wc = (wid & 1) * 64;
  const int srow = wid*32 + (lane >> 2);
  const int gcol = ((lane & 3) ^ ((lane >> 3) & 3)) * 8;   // shorts
  const int rchunk = (g ^ ((lr >> 1) & 3)) * 8;            // frag read column (shorts)
  unsigned short* lA = &As[wid*1024];
  unsigned short* lB = &Bs[wid*1024];
  const unsigned short* pA = A + (size_t)(rowBase + srow)*K + gcol;
  const unsigned short* pB = Bt + (size_t)(colBase + srow)*K + gcol;
  f32x4 acc[4][4] = {};
  for (int k0 = 0; k0 < K; k0 += 32){
    __syncthreads();
    gl_lds16(pA + k0, lA);
    gl_lds16(pA + (size_t)16*K + k0, lA + 512);
    gl_lds16(pB + k0, lB);
    gl_lds16(pB + (size_t)16*K + k0, lB + 512);
    __syncthreads();
    bf16x8 af[4], bfr[4];
    #pragma unroll
    for (int mi = 0; mi < 4; ++mi) af[mi]  = *reinterpret_cast<const bf16x8*>(&As[(wr + mi*16 + lr)*32 + rchunk]);
    #pragma unroll
    for (int ni = 0; ni < 4; ++ni) bfr[ni] = *reinterpret_cast<const bf16x8*>(&Bs[(wc + ni*16 + lr)*32 + rchunk]);
    #pragma unroll
    for (int mi = 0; mi < 4; ++mi)
      #pragma unroll
      for (int ni = 0; ni < 4; ++ni)
        acc[mi][ni] = __builtin_amdgcn_mfma_f32_16x16x32_bf16(af[mi], bfr[ni], acc[mi][ni], 0, 0, 0);
  }
  float bv[4];
  #pragma unroll
  for (int ni = 0; ni < 4; ++ni) bv[ni] = bias[colBase + wc + ni*16 + lr];
  #pragma unroll
  for (int mi = 0; mi < 4; ++mi){
    #pragma unroll
    for (int ni = 0; ni < 4; ++ni){
      #pragma unroll
      for (int j = 0; j < 4; ++j){
        int m = rowBase + wr + mi*16 + g*4 + j;
        int n = colBase + wc + ni*16 + lr;
        float v = acc[mi][ni][j] + bv[ni];
        if constexpr (MODE == 0){
          int b = m >> 11, s = m & 2047;
          int sel = n >> 9, rr = n & 511, h = rr >> 6, e = rr & 63;
          size_t bh = (size_t)(b*8 + h);
          if (sel == 0)      ob0[(bh*2048 + s)*64 + e] = f2bf(v);
          else if (sel == 1) ob1[(bh*2048 + s)*64 + e] = f2bf(v);
          else               ob2[(bh*64 + e)*2048 + s] = f2bf(v);   // V transposed
        } else if constexpr (MODE == 1 || MODE == 3){
          of[(size_t)m*N + n] = v + resid[(size_t)m*N + n];
        } else {
          ob0[(size_t)m*N + n] = f2bf(v > 0.f ? v : 0.f);
        }
      }
    }
  }
}

// ---------- flash attention, swapped QK^T (S^T = K*Q^T), 32 q/wave ----------
// grid (16, 32) = (q-tiles of 128, b*h); block 256 = 4 waves; wave owns 32 q rows (2 groups of 16).
__global__ __launch_bounds__(256) void k_attn(
    const unsigned short* __restrict__ Qb, const unsigned short* __restrict__ Kb,
    const unsigned short* __restrict__ Vt, const int* __restrict__ mask,
    const unsigned* __restrict__ mbits_p, unsigned short* __restrict__ ctx)
{
  // linear 64x64 tiles, byte-col XOR swizzle ((row&7)<<4) on writes AND reads
  __shared__ unsigned short Ks[64*64];
  __shared__ unsigned short Vs[64*64];
  __shared__ unsigned short Ps[8][16*64];   // [wave*2+qg][q(lr)][k], same XOR by q-row
  const int tid = threadIdx.x, lane = tid & 63, wid = tid >> 6;
  const int g = lane >> 4, lr = lane & 15;
  const int qt = blockIdx.x, bh = blockIdx.y;
  const int b = bh >> 3, h = bh & 7;
  const int qw = qt * 128 + wid * 32;
  const unsigned mbits = mbits_p[b*64 + qt*2] & mbits_p[b*64 + qt*2 + 1];
  const size_t mbase = (size_t)b * 2048 * 2048;
  const float SC = 0.18033688f;   // log2(e)/sqrt(64)
  const int swz = (lr & 7) << 3;  // short-index XOR for rows == lr (mod 8 invariant under +16)

  bf16x8 b_q[2][2];   // [qg][ks]: Q as B-operand, col q = lr, k(e) = ks*32 + 8g + j
  #pragma unroll
  for (int qg = 0; qg < 2; ++qg){
    const unsigned short* qp = Qb + ((size_t)bh*2048 + qw + qg*16 + lr)*64;
    b_q[qg][0] = *reinterpret_cast<const bf16x8*>(qp + g*8);
    b_q[qg][1] = *reinterpret_cast<const bf16x8*>(qp + 32 + g*8);
  }
  f32x4 acc[2][4] = {};    // [qg][ne] ctx^T frags: row e = ne*16+4g+j, col q = lr
  float m_run[2] = {-3.0e38f, -3.0e38f}, l_run[2] = {0.f, 0.f};

  // staging map: thread covers rows r0,r0+32 at 16B slot s (swizzled LDS col)
  const int r0 = tid >> 3, s = tid & 7;
  const int wcol = (s*8) ^ ((r0 & 7) << 3);       // shorts; (r0+32)&7 == r0&7
  const unsigned short* kp = Kb + (size_t)bh*2048*64 + (size_t)r0*64 + s*8;
  const unsigned short* vp = Vt + (size_t)bh*64*2048 + (size_t)r0*2048 + s*8;
  int4 kreg0, kreg1, vreg0, vreg1;

  kreg0 = *reinterpret_cast<const int4*>(kp);
  kreg1 = *reinterpret_cast<const int4*>(kp + 32*64);
  vreg0 = *reinterpret_cast<const int4*>(vp);
  vreg1 = *reinterpret_cast<const int4*>(vp + (size_t)32*2048);
  *reinterpret_cast<int4*>(&Ks[r0*64 + wcol])      = kreg0;
  *reinterpret_cast<int4*>(&Ks[(r0+32)*64 + wcol]) = kreg1;
  *reinterpret_cast<int4*>(&Vs[r0*64 + wcol])      = vreg0;
  *reinterpret_cast<int4*>(&Vs[(r0+32)*64 + wcol]) = vreg1;
  __syncthreads();

  unsigned short* myP0 = &Ps[wid*2][0];
  unsigned short* myP1 = &Ps[wid*2+1][0];

  for (int kt = 0; kt < 32; ++kt){
    if (kt < 31){   // prefetch next tile into regs (hides under compute)
      const unsigned short* kn = kp + (kt+1)*4096;
      const unsigned short* vn = vp + (kt+1)*64;
      kreg0 = *reinterpret_cast<const int4*>(kn);
      kreg1 = *reinterpret_cast<const int4*>(kn + 32*64);
      vreg0 = *reinterpret_cast<const int4*>(vn);
      vreg1 = *reinterpret_cast<const int4*>(vn + (size_t)32*2048);
    }
    // K frags once, feed both q-groups
    bf16x8 kf[4][2];
    #pragma unroll
    for (int mk = 0; mk < 4; ++mk)
      #pragma unroll
      for (int ks = 0; ks < 2; ++ks)
        kf[mk][ks] = *reinterpret_cast<const bf16x8*>(&Ks[(mk*16 + lr)*64 + ((ks*32 + g*8) ^ swz)]);
    f32x4 st[2][4] = {};
    __builtin_amdgcn_s_setprio(1);
    #pragma unroll
    for (int mk = 0; mk < 4; ++mk)
      #pragma unroll
      for (int ks = 0; ks < 2; ++ks){
        st[0][mk] = __builtin_amdgcn_mfma_f32_16x16x32_bf16(kf[mk][ks], b_q[0][ks], st[0][mk], 0,0,0);
        st[1][mk] = __builtin_amdgcn_mfma_f32_16x16x32_bf16(kf[mk][ks], b_q[1][ks], st[1][mk], 0,0,0);
      }
    __builtin_amdgcn_s_setprio(0);
    if (!((mbits >> kt) & 1)){
      const int kk0 = kt * 64;
      #pragma unroll
      for (int qg = 0; qg < 2; ++qg)
        #pragma unroll
        for (int mk = 0; mk < 4; ++mk)
          #pragma unroll
          for (int j = 0; j < 4; ++j){
            int kg = kk0 + mk*16 + g*4 + j;
            if (mask[mbase + (size_t)(qw + qg*16 + lr)*2048 + kg] == 0) st[qg][mk][j] = -3.0e30f;
          }
    }
    // per-group online softmax (log2 domain, scale folded)
    float tm[2];
    #pragma unroll
    for (int qg = 0; qg < 2; ++qg){
      float a0 = fmaxf(fmaxf(st[qg][0][0], st[qg][0][1]), fmaxf(st[qg][0][2], st[qg][0][3]));
      float a1 = fmaxf(fmaxf(st[qg][1][0], st[qg][1][1]), fmaxf(st[qg][1][2], st[qg][1][3]));
      float a2 = fmaxf(fmaxf(st[qg][2][0], st[qg][2][1]), fmaxf(st[qg][2][2], st[qg][2][3]));
      float a3 = fmaxf(fmaxf(st[qg][3][0], st[qg][3][1]), fmaxf(st[qg][3][2], st[qg][3][3]));
      float t = fmaxf(fmaxf(a0, a1), fmaxf(a2, a3));
      t = fmaxf(t, __shfl_xor(t, 16));
      t = fmaxf(t, __shfl_xor(t, 32));
      tm[qg] = t * SC;
    }
    bool ok = (tm[0] <= m_run[0] + 8.f) & (tm[1] <= m_run[1] + 8.f);
    if (!__all(ok)){   // defer-max rescale (rare)
      #pragma unroll
      for (int qg = 0; qg < 2; ++qg){
        float mnew = fmaxf(m_run[qg], tm[qg]);
        float alpha = exp2f(m_run[qg] - mnew);
        l_run[qg] *= alpha;
        #pragma unroll
        for (int ne = 0; ne < 4; ++ne)
          #pragma unroll
          for (int j = 0; j < 4; ++j) acc[qg][ne][j] *= alpha;
        m_run[qg] = mnew;
      }
    }
    #pragma unroll
    for (int qg = 0; qg < 2; ++qg){
      unsigned short* myP = qg ? myP1 : myP0;
      float mr = m_run[qg];
      float psA = 0.f, psB = 0.f;
      #pragma unroll
      for (int mk = 0; mk < 4; ++mk){
        float p0 = exp2f(__builtin_fmaf(st[qg][mk][0], SC, -mr));
        float p1 = exp2f(__builtin_fmaf(st[qg][mk][1], SC, -mr));
        float p2 = exp2f(__builtin_fmaf(st[qg][mk][2], SC, -mr));
        float p3 = exp2f(__builtin_fmaf(st[qg][mk][3], SC, -mr));
        psA += p0 + p2; psB += p1 + p3;
        uint2 uu;
        uu.x = cvt_pk_bf16(p0, p1);
        uu.y = cvt_pk_bf16(p2, p3);
        *reinterpret_cast<uint2*>(&myP[lr*64 + ((mk*16 + g*4) ^ swz)]) = uu;
      }
      float ps = psA + psB;
      ps += __shfl_xor(ps, 16);
      ps += __shfl_xor(ps, 32);
      l_run[qg] += ps;
    }
    // PV: V frags once, feed both q-groups
    #pragma unroll
    for (int ks = 0; ks < 2; ++ks){
      bf16x8 pf0 = *reinterpret_cast<const bf16x8*>(&myP0[lr*64 + ((ks*32 + g*8) ^ swz)]);
      bf16x8 pf1 = *reinterpret_cast<const bf16x8*>(&myP1[lr*64 + ((ks*32 + g*8) ^ swz)]);
      __builtin_amdgcn_s_setprio(1);
      #pragma unroll
      for (int ne = 0; ne < 4; ++ne){
        bf16x8 vf = *reinterpret_cast<const bf16x8*>(&Vs[(ne*16 + lr)*64 + ((ks*32 + g*8) ^ swz)]);
        acc[0][ne] = __builtin_amdgcn_mfma_f32_16x16x32_bf16(vf, pf0, acc[0][ne], 0,0,0);
        acc[1][ne] = __builtin_amdgcn_mfma_f32_16x16x32_bf16(vf, pf1, acc[1][ne], 0,0,0);
      }
      __builtin_amdgcn_s_setprio(0);
    }
    if (kt < 31){
      __syncthreads();   // all waves done reading Ks/Vs
      *reinterpret_cast<int4*>(&Ks[r0*64 + wcol])      = kreg0;
      *reinterpret_cast<int4*>(&Ks[(r0+32)*64 + wcol]) = kreg1;
      *reinterpret_cast<int4*>(&Vs[r0*64 + wcol])      = vreg0;
      *reinterpret_cast<int4*>(&Vs[(r0+32)*64 + wcol]) = vreg1;
      __syncthreads();   // staged tile visible
    }
  }
  #pragma unroll
  for (int qg = 0; qg < 2; ++qg){
    float inv = 1.f / l_run[qg];
    int q = qw + qg*16 + lr;
    #pragma unroll
    for (int ne = 0; ne < 4; ++ne)
      #pragma unroll
      for (int j = 0; j < 4; ++j){
        int e = ne*16 + g*4 + j;
        ctx[((size_t)b*2048 + q)*512 + h*64 + e] = f2bf(acc[qg][ne][j] * inv);
      }
  }
}

// ---------- LayerNorm: wave per row of 512 ----------
__global__ __launch_bounds__(256) void k_ln(
    const float* __restrict__ in, const float* __restrict__ gma, const float* __restrict__ bta,
    float* __restrict__ of, unsigned short* __restrict__ ob)
{
  const int lane = threadIdx.x & 63, wid = threadIdx.x >> 6;
  const size_t row = (size_t)blockIdx.x * 4 + wid;
  const float* x = in + row * 512;
  const int e0 = lane * 8;
  float xv[8];
  *reinterpret_cast<float4*>(&xv[0]) = *reinterpret_cast<const float4*>(x + e0);
  *reinterpret_cast<float4*>(&xv[4]) = *reinterpret_cast<const float4*>(x + e0 + 4);
  float s = 0.f, ss = 0.f;
  #pragma unroll
  for (int i = 0; i < 8; ++i){ s += xv[i]; ss += xv[i]*xv[i]; }
  #pragma unroll
  for (int o = 1; o < 64; o <<= 1){ s += __shfl_xor(s, o); ss += __shfl_xor(ss, o); }
  float mu = s * (1.f/512.f);
  float var = ss * (1.f/512.f) - mu*mu;
  float rs = rsqrtf(var + 1e-5f);
  float gv[8], bv[8], y[8];
  *reinterpret_cast<float4*>(&gv[0]) = *reinterpret_cast<const float4*>(gma + e0);
  *reinterpret_cast<float4*>(&gv[4]) = *reinterpret_cast<const float4*>(gma + e0 + 4);
  *reinterpret_cast<float4*>(&bv[0]) = *reinterpret_cast<const float4*>(bta + e0);
  *reinterpret_cast<float4*>(&bv[4]) = *reinterpret_cast<const float4*>(bta + e0 + 4);
  #pragma unroll
  for (int i = 0; i < 8; ++i) y[i] = (xv[i]-mu)*rs*gv[i] + bv[i];
  *reinterpret_cast<float4*>(of + row*512 + e0)     = *reinterpret_cast<float4*>(&y[0]);
  *reinterpret_cast<float4*>(of + row*512 + e0 + 4) = *reinterpret_cast<float4*>(&y[4]);
  if (ob){
    us4 o0 = { f2bf(y[0]), f2bf(y[1]), f2bf(y[2]), f2bf(y[3]) };
    us4 o1 = { f2bf(y[4]), f2bf(y[5]), f2bf(y[6]), f2bf(y[7]) };
    *reinterpret_cast<us4*>(ob + row*512 + e0)     = o0;
    *reinterpret_cast<us4*>(ob + row*512 + e0 + 4) = o1;
  }
}

extern "C" void kernel_launch(void* const* d_in, const int* in_sizes, int n_in,
                              void* d_out, int out_size, void* d_ws, size_t ws_size,
                              hipStream_t stream)
{
  const float* src  = (const float*)d_in[0];
  const int*   mask = (const int*)d_in[1];
  const float* q_w  = (const float*)d_in[2];
  const float* q_b  = (const float*)d_in[3];
  const float* k_w  = (const float*)d_in[4];
  const float* k_b  = (const float*)d_in[5];
  const float* v_w  = (const float*)d_in[6];
  const float* v_b  = (const float*)d_in[7];
  const float* o_w  = (const float*)d_in[8];
  const float* o_b  = (const float*)d_in[9];
  const float* ln1g = (const float*)d_in[10];
  const float* ln1b = (const float*)d_in[11];
  const float* w1   = (const float*)d_in[12];
  const float* b1   = (const float*)d_in[13];
  const float* w2   = (const float*)d_in[14];
  const float* b2   = (const float*)d_in[15];
  const float* ln2g = (const float*)d_in[16];
  const float* ln2b = (const float*)d_in[17];

  char* ws = (char*)d_ws;
  if (ws_size < 81795072) return;
  unsigned short* x_bf  = (unsigned short*)(ws + 0);          // 8.4MB (reused as LN1 bf16 out)
  unsigned short* wtqkv = (unsigned short*)(ws + 8388608);
  float*          bqkv  = (float*)(ws + 9961472);
  unsigned short* wto   = (unsigned short*)(ws + 9967616);
  unsigned short* wt1   = (unsigned short*)(ws + 10491904);
  unsigned short* wt2   = (unsigned short*)(ws + 12589056);
  unsigned short* Qb    = (unsigned short*)(ws + 14686208);
  unsigned short* Kb    = (unsigned short*)(ws + 23074816);
  unsigned short* Vt    = (unsigned short*)(ws + 31463424);
  unsigned short* ctx   = (unsigned short*)(ws + 39852032);
  unsigned short* ffb   = (unsigned short*)(ws + 14686208);   // overlays Q/K/Vt/ctx (dead by FF1)
  float* res = (float*)(ws + 48240640);                        // res1 then res2
  float* xf  = (float*)(ws + 65017856);
  unsigned short* mb16 = (unsigned short*)(ws + 48240640);     // bitmap in res head (dead by gemm<1>)
  const unsigned* mb32 = (const unsigned*)(ws + 48240640);
  float* outf = (float*)d_out;

  k_maskbits<<<dim3(128,2), 256, 0, stream>>>(mask, mb16);
  k_f2b<<<4096, 256, 0, stream>>>(src, x_bf, 1048576);
  k_wtrans_qkv<<<dim3(16,2,24), 256, 0, stream>>>(q_w, k_w, v_w, wtqkv);
  k_bqkv<<<6, 256, 0, stream>>>(q_b, k_b, v_b, bqkv);
  k_wtrans<<<dim3(16,16), 256, 0, stream>>>(o_w, wto, 512, 512);
  k_wtrans<<<dim3(16,64), 256, 0, stream>>>(w1, wt1, 512, 2048);
  k_wtrans<<<dim3(64,16), 256, 0, stream>>>(w2, wt2, 2048, 512);

  k_gemm<0><<<dim3(64,12), 256, 0, stream>>>(x_bf, wtqkv, bqkv, nullptr,
                                             Qb, Kb, Vt, nullptr, 8192, 1536, 512);
  k_attn<<<dim3(16,32), 256, 0, stream>>>(Qb, Kb, Vt, mask, mb32, ctx);
  k_gemm<1><<<dim3(64,4), 256, 0, stream>>>(ctx, wto, o_b, src,
                                            nullptr, nullptr, nullptr, res, 8192, 512, 512);
  k_ln<<<2048, 256, 0, stream>>>(res, ln1g, ln1b, xf, x_bf);
  k_gemm<2><<<dim3(64,16), 256, 0, stream>>>(x_bf, wt1, b1, nullptr,
                                             ffb, nullptr, nullptr, nullptr, 8192, 2048, 512);
  k_gemm<3><<<dim3(64,4), 256, 0, stream>>>(ffb, wt2, b2, xf,
                                            nullptr, nullptr, nullptr, res, 8192, 512, 2048);
  k_ln<<<2048, 256, 0, stream>>>(res, ln2g, ln2b, outf, nullptr);
}